// Round 4
// baseline (143.684 us; speedup 1.0000x reference)
//
#include <hip/hip_runtime.h>
#include <math.h>

// CascadeGCN R20: fused cooperative kernel with HAND-ROLLED grid barrier.
// R19 post-mortem: fused kernel passed but matched the pipeline (141.8us)
// with VALUBusy 2.9% / HBM 2.6% / 51 MB traffic -- ~95% of the time is
// stall. Phase-work model sums to ~30-40us; the residual ~100us is the 3x
// cg::grid_group::sync() (s_sleep backoff + conservative cache ops).
// R20: monotone-counter barrier (threadfence + relaxed agent atomicAdd,
// tight relaxed-load spin), split arrive/wait to overlap bucket-local work
// with barrier latency, shfl-based scans (18->3 barriers), register-stash
// of pairs records (one global read instead of two).
// Fallback to verified R16 pipeline retained (gate + launch-error check).

#define NB_SHIFT  8          // 256 nodes per bucket
#define BNODES    256
#define NBK       512        // level-1 key space (nb = 391, padded)
#define CAP       8192       // bucket capacity (mean 6400, +22 sigma)
#define CAP_SHIFT 13
#define CHUNK     4888       // 512 chunks over E=2.5M
#define PBLK      512        // 8 waves
#define RPT       16         // CAP / PBLK: max records per thread

struct SMemP0 {                       // partition phase
    int sp[CHUNK];                    // packed records (dlow<<24 | src)
    unsigned short sb[CHUNK];         // bucket ids
    int cnt[NBK], ofs[NBK], cur[NBK], gbase[NBK];
    int wtmp[8];
};
struct SMemP1 {                       // bucket phases
    int stage2[CAP];                  // node-sorted src ids (persists)
    int ofs[BNODES], cnt[BNODES], cur[BNODES];
    float w1[160], bb1[32], w2[32];
    int wtmp[8];
};
union SMem { SMemP0 p0; SMemP1 p1; };

// ---- monotone grid barrier: arrive (release) / wait (acquire) ----
__device__ __forceinline__ void gbar_arrive(int* bar, int tid) {
    __syncthreads();                       // all waves' work complete
    if (tid == 0) {
        __threadfence();                   // release: flush block's writes
        __hip_atomic_fetch_add(bar, 1, __ATOMIC_RELAXED,
                               __HIP_MEMORY_SCOPE_AGENT);
    }
}
__device__ __forceinline__ void gbar_wait(int* bar, int tgt, int tid) {
    if (tid == 0) {
        while (__hip_atomic_load(bar, __ATOMIC_RELAXED,
                                 __HIP_MEMORY_SCOPE_AGENT) < tgt)
            __builtin_amdgcn_s_sleep(1);
        __threadfence();                   // acquire: invalidate L1/L2
    }
    __syncthreads();
}

__global__ __launch_bounds__(PBLK, 4) void k_fused(
        const int* __restrict__ src, const int* __restrict__ dst, int E,
        const float* __restrict__ x,
        const float* __restrict__ W1, const float* __restrict__ b1,
        const float* __restrict__ W2, const float* __restrict__ b2,
        float* __restrict__ out,
        int* __restrict__ pairs, int* __restrict__ bcur, int* __restrict__ gbar,
        float* __restrict__ h2s, float* __restrict__ xs, int n, int nb) {
    __shared__ SMem sm;
    const int tid  = threadIdx.x;
    const int blk  = blockIdx.x;
    const int G    = gridDim.x;
    const int lane = tid & 63, wv = tid >> 6;
    const int nbase = blk << NB_SHIFT;

    // ---------- phase 0: LDS bucket partition ----------
    {
        int base = blk * CHUNK;
        if (base < E) {
            int m = min(CHUNK, E - base);
            sm.p0.cnt[tid] = 0;                       // NBK == PBLK
            __syncthreads();
            for (int i = tid; i < m; i += 2 * PBLK) { // histogram, 2x unrolled
                int i1 = i + PBLK;
                int k0 = dst[base + i] >> NB_SHIFT;
                int k1 = (i1 < m) ? (dst[base + i1] >> NB_SHIFT) : -1;
                atomicAdd(&sm.p0.cnt[k0], 1);
                if (k1 >= 0) atomicAdd(&sm.p0.cnt[k1], 1);
            }
            __syncthreads();
            // exclusive scan over 512 via shfl (2-level, 3 barriers)
            int v = sm.p0.cnt[tid];
            int s = v;
#pragma unroll
            for (int d = 1; d < 64; d <<= 1) {
                int t = __shfl_up(s, d);
                if (lane >= d) s += t;
            }
            if (lane == 63) sm.p0.wtmp[wv] = s;
            __syncthreads();
            if (wv == 0) {
                int t = (lane < 8) ? sm.p0.wtmp[lane] : 0;
#pragma unroll
                for (int d = 1; d < 8; d <<= 1) {
                    int u = __shfl_up(t, d);
                    if (lane >= d) t += u;
                }
                if (lane < 8) sm.p0.wtmp[lane] = t;
            }
            __syncthreads();
            int pre = s + (wv ? sm.p0.wtmp[wv - 1] : 0) - v;
            sm.p0.ofs[tid] = pre;
            sm.p0.cur[tid] = pre;
            sm.p0.gbase[tid] = (tid << CAP_SHIFT)
                             + (v ? atomicAdd(&bcur[tid], v) : 0);
            __syncthreads();
            // bucket-ordered scatter into LDS (4x unrolled)
            for (int i = tid; i < m; i += 4 * PBLK) {
                int ia = i + PBLK, ib = i + 2 * PBLK, ic = i + 3 * PBLK;
                int s0 = src[base + i], d0 = dst[base + i];
                int s1 = 0, d1 = 0, s2 = 0, d2 = 0, s3 = 0, d3 = 0;
                if (ia < m) { s1 = src[base + ia]; d1 = dst[base + ia]; }
                if (ib < m) { s2 = src[base + ib]; d2 = dst[base + ib]; }
                if (ic < m) { s3 = src[base + ic]; d3 = dst[base + ic]; }
                int b0 = d0 >> NB_SHIFT;
                int p0 = atomicAdd(&sm.p0.cur[b0], 1);
                sm.p0.sp[p0] = ((d0 & (BNODES - 1)) << 24) | s0;
                sm.p0.sb[p0] = (unsigned short)b0;
                if (ia < m) {
                    int b1k = d1 >> NB_SHIFT;
                    int p1 = atomicAdd(&sm.p0.cur[b1k], 1);
                    sm.p0.sp[p1] = ((d1 & (BNODES - 1)) << 24) | s1;
                    sm.p0.sb[p1] = (unsigned short)b1k;
                }
                if (ib < m) {
                    int b2k = d2 >> NB_SHIFT;
                    int p2 = atomicAdd(&sm.p0.cur[b2k], 1);
                    sm.p0.sp[p2] = ((d2 & (BNODES - 1)) << 24) | s2;
                    sm.p0.sb[p2] = (unsigned short)b2k;
                }
                if (ic < m) {
                    int b3k = d3 >> NB_SHIFT;
                    int p3 = atomicAdd(&sm.p0.cur[b3k], 1);
                    sm.p0.sp[p3] = ((d3 & (BNODES - 1)) << 24) | s3;
                    sm.p0.sb[p3] = (unsigned short)b3k;
                }
            }
            __syncthreads();
            for (int i = tid; i < m; i += PBLK) {     // coalesced-run writeout
                int b = sm.p0.sb[i];
                pairs[sm.p0.gbase[b] + (i - sm.p0.ofs[b])] = sm.p0.sp[i];
            }
        }
    }
    // ---- barrier 1 (pairs+bcur); overlap: weights, x-preload, cnt zero ----
    gbar_arrive(gbar, tid);
    float xr0 = 0.f, xr1 = 0.f, xr2 = 0.f, xr3 = 0.f, xr4 = 0.f;
    if (blk < nb) {
        if (tid < 160) sm.p1.w1[tid] = W1[tid];
        else if (tid < 192) sm.p1.bb1[tid - 160] = b1[tid - 160];
        else if (tid < 224) sm.p1.w2[tid - 192] = W2[tid - 192];
        if (tid < BNODES) {
            sm.p1.cnt[tid] = 0;
            int node = nbase + tid;
            if (node < n) {                           // raw features into regs
                const float* xp = x + (size_t)node * 5;
                xr0 = xp[0]; xr1 = xp[1]; xr2 = xp[2]; xr3 = xp[3]; xr4 = xp[4];
            }
        }
    }
    gbar_wait(gbar, G, tid);

    // ---------- phase A: reg-stash records, histogram, scan, xs ----------
    int nrec = 0;
    int rec[RPT];
    if (blk < nb) {
        int base = blk << CAP_SHIFT;
        int len = min(((volatile int*)bcur)[blk], CAP);   // vector load (no K$)
#pragma unroll
        for (int j = 0; j < RPT; ++j) {               // one global pass -> regs
            int i = tid + j * PBLK;
            if (i < len) { rec[j] = pairs[base + i]; nrec = j + 1; }
        }
#pragma unroll
        for (int j = 0; j < RPT; ++j)                 // node histogram
            if (j < nrec) atomicAdd(&sm.p1.cnt[((unsigned)rec[j]) >> 24], 1);
        __syncthreads();
        // exclusive scan over 256 via shfl (2-level)
        int v = (tid < BNODES) ? sm.p1.cnt[tid] : 0;
        int s = v;
#pragma unroll
        for (int d = 1; d < 64; d <<= 1) {
            int t = __shfl_up(s, d);
            if (lane >= d) s += t;
        }
        if (lane == 63 && wv < 4) sm.p1.wtmp[wv] = s;
        __syncthreads();
        if (wv == 0) {
            int t = (lane < 4) ? sm.p1.wtmp[lane] : 0;
#pragma unroll
            for (int d = 1; d < 4; d <<= 1) {
                int u = __shfl_up(t, d);
                if (lane >= d) t += u;
            }
            if (lane < 4) sm.p1.wtmp[lane] = t;
        }
        __syncthreads();
        if (tid < BNODES) {
            int pre = s + (wv ? sm.p1.wtmp[wv - 1] : 0) - v;
            sm.p1.ofs[tid] = pre;
            sm.p1.cur[tid] = pre;
            int node = nbase + tid;
            if (node < n) {                           // dinv-scaled features
                float di = rsqrtf((float)v + 1.0f);
                float* xo = xs + ((size_t)node << 3); // padded row: 8 floats
                xo[0] = xr0 * di; xo[1] = xr1 * di; xo[2] = xr2 * di;
                xo[3] = xr3 * di; xo[4] = xr4 * di;
            }
        }
    }
    // ---- barrier 2 (xs); overlap: counting-sort scatter (LDS-local) ----
    gbar_arrive(gbar, tid);
    if (blk < nb) {
#pragma unroll
        for (int j = 0; j < RPT; ++j)
            if (j < nrec) {
                int p = atomicAdd(&sm.p1.cur[((unsigned)rec[j]) >> 24], 1);
                sm.p1.stage2[p] = rec[j] & 0x00FFFFFF;
            }
    }
    gbar_wait(gbar, 2 * G, tid);

    // ---------- phase B: layer-1 aggregation from LDS-resident stage2 ------
    if (blk < nb) {
        int t2 = tid >> 1, half = tid & 1;            // 2 threads/node
        int node = nbase + t2;
        if (node < n) {
            int beg = sm.p1.ofs[t2], dg = sm.p1.cnt[t2];
            float a0 = 0.f, a1 = 0.f, a2 = 0.f, a3 = 0.f, a4 = 0.f;
            if (!half) {                              // self-loop term
                const float* xo = xs + ((size_t)node << 3);
                a0 = xo[0]; a1 = xo[1]; a2 = xo[2]; a3 = xo[3]; a4 = xo[4];
            }
            for (int e = beg + half; e < beg + dg; e += 2) {
                int sidx = sm.p1.stage2[e];
                const float* xr = xs + ((size_t)sidx << 3);
                float4 q = *(const float4*)xr;
                float q4 = xr[4];
                a0 += q.x; a1 += q.y; a2 += q.z; a3 += q.w; a4 += q4;
            }
            a0 += __shfl_xor(a0, 1); a1 += __shfl_xor(a1, 1);
            a2 += __shfl_xor(a2, 1); a3 += __shfl_xor(a3, 1);
            a4 += __shfl_xor(a4, 1);
            if (!half) {
                float di = rsqrtf((float)dg + 1.0f);
                a0 *= di; a1 *= di; a2 *= di; a3 *= di; a4 *= di;
                float sum = 0.f;
#pragma unroll
                for (int c = 0; c < 32; ++c) {
                    float z = sm.p1.bb1[c] + a0 * sm.p1.w1[c]
                            + a1 * sm.p1.w1[32 + c] + a2 * sm.p1.w1[64 + c]
                            + a3 * sm.p1.w1[96 + c] + a4 * sm.p1.w1[128 + c];
                    sum += fmaxf(z, 0.f) * sm.p1.w2[c];
                }
                h2s[node] = sum * di;                 // pre-scale by src dinv
            }
        }
    }
    // ---- barrier 3 (h2s) ----
    gbar_arrive(gbar, tid);
    gbar_wait(gbar, 3 * G, tid);

    // ---------- phase C: layer-2 from LDS-resident stage2 ------------------
    if (blk < nb) {
        int t2 = tid >> 1, half = tid & 1;
        int node = nbase + t2;
        if (node >= n) return;
        int beg = sm.p1.ofs[t2], dg = sm.p1.cnt[t2];
        float a = 0.f;
        for (int e = beg + half; e < beg + dg; e += 2)
            a += h2s[sm.p1.stage2[e]];
        a += __shfl_xor(a, 1);
        if (!half) {
            float di = rsqrtf((float)dg + 1.0f);
            float vv = di * (a + h2s[node]) + b2[0];
            out[node] = 1.0f / (1.0f + __expf(-vv));
        }
    }
}

// ===================== fallback: verified R16 pipeline =====================

__global__ __launch_bounds__(512) void k_part(const int* __restrict__ src,
                                              const int* __restrict__ dst, int E,
                                              int* __restrict__ bcur,
                                              int* __restrict__ pairs) {
    __shared__ int sp[CHUNK];
    __shared__ unsigned short sb[CHUNK];
    __shared__ int cnt[NBK], ofs[NBK], cur[NBK], gbase[NBK];
    int tid = threadIdx.x;
    int base = blockIdx.x * CHUNK;
    int m = min(CHUNK, E - base);

    if (tid < NBK) cnt[tid] = 0;
    __syncthreads();
    for (int i = tid; i < m; i += 2 * 512) {
        int i1 = i + 512;
        int k0 = dst[base + i] >> NB_SHIFT;
        int k1 = (i1 < m) ? (dst[base + i1] >> NB_SHIFT) : -1;
        atomicAdd(&cnt[k0], 1);
        if (k1 >= 0) atomicAdd(&cnt[k1], 1);
    }
    __syncthreads();
    int v = cnt[tid];
    ofs[tid] = v;
    __syncthreads();
    for (int off = 1; off < NBK; off <<= 1) {
        int u = (tid >= off) ? ofs[tid - off] : 0;
        __syncthreads();
        ofs[tid] += u;
        __syncthreads();
    }
    int pre = ofs[tid] - v;
    ofs[tid] = pre;
    cur[tid] = pre;
    gbase[tid] = (tid << CAP_SHIFT) + (v ? atomicAdd(&bcur[tid], v) : 0);
    __syncthreads();
    for (int i = tid; i < m; i += 4 * 512) {
        int ia = i + 512, ib = i + 1024, ic = i + 1536;
        int s0 = src[base + i], d0 = dst[base + i];
        int s1 = 0, d1 = 0, s2 = 0, d2 = 0, s3 = 0, d3 = 0;
        if (ia < m) { s1 = src[base + ia]; d1 = dst[base + ia]; }
        if (ib < m) { s2 = src[base + ib]; d2 = dst[base + ib]; }
        if (ic < m) { s3 = src[base + ic]; d3 = dst[base + ic]; }
        int b0 = d0 >> NB_SHIFT;
        int p0 = atomicAdd(&cur[b0], 1);
        sp[p0] = ((d0 & (BNODES - 1)) << 24) | s0;
        sb[p0] = (unsigned short)b0;
        if (ia < m) {
            int b1 = d1 >> NB_SHIFT;
            int p1 = atomicAdd(&cur[b1], 1);
            sp[p1] = ((d1 & (BNODES - 1)) << 24) | s1;
            sb[p1] = (unsigned short)b1;
        }
        if (ib < m) {
            int b2 = d2 >> NB_SHIFT;
            int p2 = atomicAdd(&cur[b2], 1);
            sp[p2] = ((d2 & (BNODES - 1)) << 24) | s2;
            sb[p2] = (unsigned short)b2;
        }
        if (ic < m) {
            int b3 = d3 >> NB_SHIFT;
            int p3 = atomicAdd(&cur[b3], 1);
            sp[p3] = ((d3 & (BNODES - 1)) << 24) | s3;
            sb[p3] = (unsigned short)b3;
        }
    }
    __syncthreads();
    for (int i = tid; i < m; i += 512) {
        int b = sb[i];
        pairs[gbase[b] + (i - ofs[b])] = sp[i];
    }
}

__global__ __launch_bounds__(512) void k_sorta(const int* __restrict__ pairs,
                                               const int* __restrict__ bcur,
                                               const float* __restrict__ x,
                                               float* __restrict__ dinv,
                                               float* __restrict__ xs,
                                               int* __restrict__ nofs,
                                               int* __restrict__ deg, int n) {
    __shared__ int cnt[BNODES], scn[BNODES];
    int tid = threadIdx.x;
    int b = blockIdx.x;
    int base = b << CAP_SHIFT;
    int len = min(bcur[b], CAP);

    if (tid < BNODES) cnt[tid] = 0;
    __syncthreads();
    for (int i = tid; i < len; i += 512)
        atomicAdd(&cnt[((unsigned)pairs[base + i]) >> 24], 1);
    __syncthreads();
    int v = (tid < BNODES) ? cnt[tid] : 0;
    if (tid < BNODES) scn[tid] = v;
    __syncthreads();
    for (int off = 1; off < BNODES; off <<= 1) {
        int u = (tid < BNODES && tid >= off) ? scn[tid - off] : 0;
        __syncthreads();
        if (tid < BNODES) scn[tid] += u;
        __syncthreads();
    }
    if (tid < BNODES) {
        int node = (b << NB_SHIFT) + tid;
        if (node < n) {
            nofs[node] = base + scn[tid] - v;
            deg[node] = v;
            float di = rsqrtf((float)v + 1.0f);
            dinv[node] = di;
            const float* xr = x + (size_t)node * 5;
            float* xo = xs + ((size_t)node << 3);
#pragma unroll
            for (int k = 0; k < 5; ++k) xo[k] = xr[k] * di;
        }
    }
}

__global__ __launch_bounds__(512) void k_sortagg1(int* __restrict__ pairs,
                                                  const int* __restrict__ bcur,
                                                  const int* __restrict__ nofs,
                                                  const int* __restrict__ deg,
                                                  const float* __restrict__ xs,
                                                  const float* __restrict__ dinv,
                                                  const float* __restrict__ W1,
                                                  const float* __restrict__ b1,
                                                  const float* __restrict__ W2,
                                                  float* __restrict__ h2s, int n) {
    __shared__ int stage2[CAP];
    __shared__ int ofs[BNODES], cnt[BNODES], cur[BNODES];
    __shared__ float w1[160], bb1[32], w2[32];
    int tid = threadIdx.x;
    int b = blockIdx.x;
    int nbase = b << NB_SHIFT;
    int base = b << CAP_SHIFT;
    int len = min(bcur[b], CAP);

    if (tid < 160) w1[tid] = W1[tid];
    else if (tid < 192) bb1[tid - 160] = b1[tid - 160];
    else if (tid < 224) w2[tid - 192] = W2[tid - 192];
    if (tid < BNODES) {
        int node = nbase + tid;
        int o = 0, c = 0;
        if (node < n) { o = nofs[node] - base; c = deg[node]; }
        ofs[tid] = o; cnt[tid] = c; cur[tid] = o;
    }
    __syncthreads();
    for (int i = tid; i < len; i += 2048) {
        int ia = i + 512, ib = i + 1024, ic = i + 1536;
        int v0 = pairs[base + i];
        int v1 = (ia < len) ? pairs[base + ia] : -1;
        int v2 = (ib < len) ? pairs[base + ib] : -1;
        int v3 = (ic < len) ? pairs[base + ic] : -1;
        int p0 = atomicAdd(&cur[((unsigned)v0) >> 24], 1);
        stage2[p0] = v0 & 0x00FFFFFF;
        if (v1 != -1) {
            int p1 = atomicAdd(&cur[((unsigned)v1) >> 24], 1);
            stage2[p1] = v1 & 0x00FFFFFF;
        }
        if (v2 != -1) {
            int p2 = atomicAdd(&cur[((unsigned)v2) >> 24], 1);
            stage2[p2] = v2 & 0x00FFFFFF;
        }
        if (v3 != -1) {
            int p3 = atomicAdd(&cur[((unsigned)v3) >> 24], 1);
            stage2[p3] = v3 & 0x00FFFFFF;
        }
    }
    __syncthreads();
    {
        int len4 = len >> 2;
        const int4* s4 = (const int4*)stage2;
        int4* p4 = (int4*)(pairs + base);
        for (int i = tid; i < len4; i += 512) p4[i] = s4[i];
        for (int i = (len4 << 2) + tid; i < len; i += 512)
            pairs[base + i] = stage2[i];
    }
    int t2 = tid >> 1, half = tid & 1;
    int node = nbase + t2;
    if (node >= n) return;
    int beg = ofs[t2], dg = cnt[t2];
    float a0 = 0.f, a1 = 0.f, a2 = 0.f, a3 = 0.f, a4 = 0.f;
    if (!half) {
        const float* xo = xs + ((size_t)node << 3);
        a0 = xo[0]; a1 = xo[1]; a2 = xo[2]; a3 = xo[3]; a4 = xo[4];
    }
    for (int e = beg + half; e < beg + dg; e += 2) {
        int s = stage2[e];
        const float* xr = xs + ((size_t)s << 3);
        float4 q = *(const float4*)xr;
        float q4 = xr[4];
        a0 += q.x; a1 += q.y; a2 += q.z; a3 += q.w; a4 += q4;
    }
    a0 += __shfl_xor(a0, 1); a1 += __shfl_xor(a1, 1); a2 += __shfl_xor(a2, 1);
    a3 += __shfl_xor(a3, 1); a4 += __shfl_xor(a4, 1);
    if (half) return;
    float di = dinv[node];
    a0 *= di; a1 *= di; a2 *= di; a3 *= di; a4 *= di;
    float sum = 0.f;
#pragma unroll
    for (int c = 0; c < 32; ++c) {
        float z = bb1[c] + a0 * w1[c] + a1 * w1[32 + c] + a2 * w1[64 + c]
                         + a3 * w1[96 + c] + a4 * w1[128 + c];
        sum += fmaxf(z, 0.f) * w2[c];
    }
    h2s[node] = sum * di;
}

__global__ __launch_bounds__(256) void k_agg2(const int* __restrict__ pairs,
                                              const int* __restrict__ nofs,
                                              const int* __restrict__ deg,
                                              const float* __restrict__ h2s,
                                              const float* __restrict__ dinv,
                                              const float* __restrict__ b2,
                                              float* __restrict__ out, int n) {
    int tid = threadIdx.x;
    int node = blockIdx.x * 64 + (tid >> 2);
    int q = tid & 3;
    if (node >= n) return;
    int beg = nofs[node], dg = deg[node];
    float a = 0.f;
    for (int e = beg + q; e < beg + dg; e += 4) a += h2s[pairs[e]];
    a += __shfl_xor(a, 1);
    a += __shfl_xor(a, 2);
    if (q) return;
    float v = dinv[node] * (a + h2s[node]) + b2[0];
    out[node] = 1.0f / (1.0f + __expf(-v));
}

extern "C" void kernel_launch(void* const* d_in, const int* in_sizes, int n_in,
                              void* d_out, int out_size, void* d_ws, size_t ws_size,
                              hipStream_t stream) {
    const float* x  = (const float*)d_in[0];
    const int*   ei = (const int*)d_in[1];
    const float* W1 = (const float*)d_in[2];
    const float* b1 = (const float*)d_in[3];
    const float* W2 = (const float*)d_in[4];
    const float* b2 = (const float*)d_in[5];
    float* out = (float*)d_out;

    const int n = in_sizes[0] / 5;       // 100000
    const int E = in_sizes[1] / 2;       // 2500000
    const int* src = ei;
    const int* dst = ei + E;
    const int nb = (n + BNODES - 1) >> NB_SHIFT;   // 391

    // unified ws (4B units): [pairs (nb+1)<<13][bcur NBK][gbar 16]
    //                        [deg n][nofs n][dinv n][h2s n][xs 8n]
    int* wsi = (int*)d_ws;
    int*   pairs = wsi;
    int*   bcur  = wsi + ((size_t)(nb + 1) << CAP_SHIFT);
    int*   gbar  = bcur + NBK;
    int*   deg   = gbar + 16;
    int*   nofs  = deg + n;
    float* dinv  = (float*)(nofs + n);
    float* h2s   = dinv + n;
    float* xs    = h2s + n;

    const int nchunk = (E + CHUNK - 1) / CHUNK;    // 512
    const int g = nchunk > nb ? nchunk : nb;       // 512

    // one-time host-side gate: can g blocks be co-resident?
    static int use_coop = -1;
    if (use_coop < 0) {
        int dev = 0, ncu = 0, maxb = 0;
        hipGetDevice(&dev);
        hipDeviceGetAttribute(&ncu, hipDeviceAttributeMultiprocessorCount, dev);
        hipError_t e = hipOccupancyMaxActiveBlocksPerMultiprocessor(
                &maxb, k_fused, PBLK, 0);
        int coop = 0;
        hipDeviceGetAttribute(&coop, hipDeviceAttributeCooperativeLaunch, dev);
        use_coop = (e == hipSuccess && coop && (long)maxb * ncu >= g) ? 1 : 0;
    }

    hipMemsetAsync(bcur, 0, (NBK + 16) * sizeof(int), stream);  // bcur + gbar

    if (use_coop) {
        void* args[] = {(void*)&src, (void*)&dst, (void*)&E, (void*)&x,
                        (void*)&W1, (void*)&b1, (void*)&W2, (void*)&b2,
                        (void*)&out, (void*)&pairs, (void*)&bcur, (void*)&gbar,
                        (void*)&h2s, (void*)&xs, (void*)&n, (void*)&nb};
        hipError_t e = hipLaunchCooperativeKernel((const void*)k_fused,
                                                  dim3(g), dim3(PBLK),
                                                  args, 0, stream);
        if (e == hipSuccess) return;
        use_coop = 0;                    // launch refused -> permanent fallback
    }

    // fallback: verified R16 pipeline
    const int nagg = (n + 63) / 64;
    k_part<<<nchunk, 512, 0, stream>>>(src, dst, E, bcur, pairs);
    k_sorta<<<nb, 512, 0, stream>>>(pairs, bcur, x, dinv, xs, nofs, deg, n);
    k_sortagg1<<<nb, 512, 0, stream>>>(pairs, bcur, nofs, deg, xs, dinv,
                                       W1, b1, W2, h2s, n);
    k_agg2<<<nagg, 256, 0, stream>>>(pairs, nofs, deg, h2s, dinv, b2, out, n);
}

// Round 6
// 141.636 us; speedup vs baseline: 1.0145x; 1.0145x over previous
//
#include <hip/hip_runtime.h>
#include <math.h>

// CascadeGCN R22 (= R21 resubmit; prior bench died in container acquisition,
// not in the kernel -- audited for deadlock/alignment/occupancy, none found).
// Theory: wall = ~93us harness workspace-poison + ~50us kernel. R21/22 cuts
// kernel work: phase 0 edge list read ONCE as int4 into registers (was dst
// twice + src once, scalar), phase A pairs re-read as int4, barrier arrivals
// distributed over 8 cachelines. Fallback to verified R16 pipeline retained.

#define NB_SHIFT  8          // 256 nodes per bucket
#define BNODES    256
#define NBK       512        // level-1 key space (nb = 391, padded)
#define CAP       8192       // bucket capacity (mean 6400, +22 sigma)
#define CAP_SHIFT 13
#define CHUNK     4888       // 512 chunks over E=2.5M
#define PBLK      512        // 8 waves
#define RPT0      3          // ceil(CHUNK/4/PBLK) int4 slots per thread
#define RPT4      4          // CAP/4/PBLK int4 slots per thread
#define GBS       16         // gbar counter stride in ints (64B lines)

struct SMemP0 {                       // partition phase
    int sp[CHUNK];                    // packed records (dlow<<24 | src)
    unsigned short sb[CHUNK];         // bucket ids
    int cnt[NBK], ofs[NBK], cur[NBK], gbase[NBK];
    int wtmp[8];
};
struct SMemP1 {                       // bucket phases
    int stage2[CAP];                  // node-sorted src ids (persists)
    int ofs[BNODES], cnt[BNODES], cur[BNODES];
    float w1[160], bb1[32], w2[32];
    int wtmp[8];
};
union SMem { SMemP0 p0; SMemP1 p1; };

// ---- monotone grid barrier, 8-way distributed arrival counters ----
__device__ __forceinline__ void gbar_arrive(int* bar, int blk, int tid) {
    __syncthreads();                       // all waves' work complete
    if (tid == 0) {
        __threadfence();                   // release
        __hip_atomic_fetch_add(&bar[(blk & 7) * GBS], 1, __ATOMIC_RELAXED,
                               __HIP_MEMORY_SCOPE_AGENT);
    }
}
__device__ __forceinline__ void gbar_wait(int* bar, int tgt, int tid) {
    if (tid == 0) {
        for (;;) {
            int s = 0;
#pragma unroll
            for (int k = 0; k < 8; ++k)
                s += __hip_atomic_load(&bar[k * GBS], __ATOMIC_RELAXED,
                                       __HIP_MEMORY_SCOPE_AGENT);
            if (s >= tgt) break;
            __builtin_amdgcn_s_sleep(1);
        }
        __threadfence();                   // acquire
    }
    __syncthreads();
}

__global__ __launch_bounds__(PBLK, 4) void k_fused(
        const int* __restrict__ src, const int* __restrict__ dst, int E,
        const float* __restrict__ x,
        const float* __restrict__ W1, const float* __restrict__ b1,
        const float* __restrict__ W2, const float* __restrict__ b2,
        float* __restrict__ out,
        int* __restrict__ pairs, int* __restrict__ bcur, int* __restrict__ gbar,
        float* __restrict__ h2s, float* __restrict__ xs, int n, int nb) {
    __shared__ SMem sm;
    const int tid  = threadIdx.x;
    const int blk  = blockIdx.x;
    const int G    = gridDim.x;
    const int lane = tid & 63, wv = tid >> 6;
    const int nbase = blk << NB_SHIFT;

    // ---------- phase 0: single-pass int4 reg-stash bucket partition --------
    {
        int base = blk * CHUNK;
        if (base < E) {
            int m = min(CHUNK, E - base);
            int m4 = m >> 2;
            int4 dv[RPT0], sv[RPT0];
            int nv = 0;
            const int4* d4 = (const int4*)(dst + base);   // base%4==0: aligned
            const int4* s4g = (const int4*)(src + base);
#pragma unroll
            for (int j = 0; j < RPT0; ++j) {              // ONE global pass
                int idx = tid + j * PBLK;
                if (idx < m4) { dv[j] = d4[idx]; sv[j] = s4g[idx]; nv = j + 1; }
            }
            int tb = (m4 << 2) + tid;                     // scalar tail (<4)
            int td = 0, ts = 0, tvalid = 0;
            if (tb < m) { td = dst[base + tb]; ts = src[base + tb]; tvalid = 1; }
            sm.p0.cnt[tid] = 0;                           // NBK == PBLK
            __syncthreads();
#pragma unroll
            for (int j = 0; j < RPT0; ++j) if (j < nv) {  // histogram from regs
                atomicAdd(&sm.p0.cnt[dv[j].x >> NB_SHIFT], 1);
                atomicAdd(&sm.p0.cnt[dv[j].y >> NB_SHIFT], 1);
                atomicAdd(&sm.p0.cnt[dv[j].z >> NB_SHIFT], 1);
                atomicAdd(&sm.p0.cnt[dv[j].w >> NB_SHIFT], 1);
            }
            if (tvalid) atomicAdd(&sm.p0.cnt[td >> NB_SHIFT], 1);
            __syncthreads();
            // exclusive scan over 512 via shfl (2-level)
            int v = sm.p0.cnt[tid];
            int s = v;
#pragma unroll
            for (int d = 1; d < 64; d <<= 1) {
                int t = __shfl_up(s, d);
                if (lane >= d) s += t;
            }
            if (lane == 63) sm.p0.wtmp[wv] = s;
            __syncthreads();
            if (wv == 0) {
                int t = (lane < 8) ? sm.p0.wtmp[lane] : 0;
#pragma unroll
                for (int d = 1; d < 8; d <<= 1) {
                    int u = __shfl_up(t, d);
                    if (lane >= d) t += u;
                }
                if (lane < 8) sm.p0.wtmp[lane] = t;
            }
            __syncthreads();
            int pre = s + (wv ? sm.p0.wtmp[wv - 1] : 0) - v;
            sm.p0.ofs[tid] = pre;
            sm.p0.cur[tid] = pre;
            sm.p0.gbase[tid] = (tid << CAP_SHIFT)
                             + (v ? atomicAdd(&bcur[tid], v) : 0);
            __syncthreads();
            // bucket-ordered scatter from regs into LDS
#pragma unroll
            for (int j = 0; j < RPT0; ++j) if (j < nv) {
                int b, p;
                b = dv[j].x >> NB_SHIFT; p = atomicAdd(&sm.p0.cur[b], 1);
                sm.p0.sp[p] = ((dv[j].x & (BNODES - 1)) << 24) | sv[j].x;
                sm.p0.sb[p] = (unsigned short)b;
                b = dv[j].y >> NB_SHIFT; p = atomicAdd(&sm.p0.cur[b], 1);
                sm.p0.sp[p] = ((dv[j].y & (BNODES - 1)) << 24) | sv[j].y;
                sm.p0.sb[p] = (unsigned short)b;
                b = dv[j].z >> NB_SHIFT; p = atomicAdd(&sm.p0.cur[b], 1);
                sm.p0.sp[p] = ((dv[j].z & (BNODES - 1)) << 24) | sv[j].z;
                sm.p0.sb[p] = (unsigned short)b;
                b = dv[j].w >> NB_SHIFT; p = atomicAdd(&sm.p0.cur[b], 1);
                sm.p0.sp[p] = ((dv[j].w & (BNODES - 1)) << 24) | sv[j].w;
                sm.p0.sb[p] = (unsigned short)b;
            }
            if (tvalid) {
                int b = td >> NB_SHIFT;
                int p = atomicAdd(&sm.p0.cur[b], 1);
                sm.p0.sp[p] = ((td & (BNODES - 1)) << 24) | ts;
                sm.p0.sb[p] = (unsigned short)b;
            }
            __syncthreads();
            for (int i = tid; i < m; i += PBLK) {         // coalesced writeout
                int b = sm.p0.sb[i];
                pairs[sm.p0.gbase[b] + (i - sm.p0.ofs[b])] = sm.p0.sp[i];
            }
        }
    }
    // ---- barrier 1 (pairs+bcur); overlap: weights, x-preload, cnt zero ----
    gbar_arrive(gbar, blk, tid);
    float xr0 = 0.f, xr1 = 0.f, xr2 = 0.f, xr3 = 0.f, xr4 = 0.f;
    if (blk < nb) {
        if (tid < 160) sm.p1.w1[tid] = W1[tid];
        else if (tid < 192) sm.p1.bb1[tid - 160] = b1[tid - 160];
        else if (tid < 224) sm.p1.w2[tid - 192] = W2[tid - 192];
        if (tid < BNODES) {
            sm.p1.cnt[tid] = 0;
            int node = nbase + tid;
            if (node < n) {                               // raw features -> regs
                const float* xp = x + (size_t)node * 5;
                xr0 = xp[0]; xr1 = xp[1]; xr2 = xp[2]; xr3 = xp[3]; xr4 = xp[4];
            }
        }
    }
    gbar_wait(gbar, G, tid);

    // ---------- phase A: int4 reg-stash records, histogram, scan, xs --------
    int4 rc[RPT4];
    int nv4 = 0, rt = 0, rtv = 0;
    if (blk < nb) {
        int base = blk << CAP_SHIFT;
        int len = min(((volatile int*)bcur)[blk], CAP);
        int len4 = len >> 2;
        const int4* p4 = (const int4*)(pairs + base);     // 32KB-aligned
#pragma unroll
        for (int j = 0; j < RPT4; ++j) {                  // ONE global pass
            int idx = tid + j * PBLK;
            if (idx < len4) { rc[j] = p4[idx]; nv4 = j + 1; }
        }
        int i = (len4 << 2) + tid;                        // tail (<4 records)
        if (i < len) { rt = pairs[base + i]; rtv = 1; }
#pragma unroll
        for (int j = 0; j < RPT4; ++j) if (j < nv4) {     // node histogram
            atomicAdd(&sm.p1.cnt[((unsigned)rc[j].x) >> 24], 1);
            atomicAdd(&sm.p1.cnt[((unsigned)rc[j].y) >> 24], 1);
            atomicAdd(&sm.p1.cnt[((unsigned)rc[j].z) >> 24], 1);
            atomicAdd(&sm.p1.cnt[((unsigned)rc[j].w) >> 24], 1);
        }
        if (rtv) atomicAdd(&sm.p1.cnt[((unsigned)rt) >> 24], 1);
        __syncthreads();
        // exclusive scan over 256 via shfl (2-level)
        int v = (tid < BNODES) ? sm.p1.cnt[tid] : 0;
        int s = v;
#pragma unroll
        for (int d = 1; d < 64; d <<= 1) {
            int t = __shfl_up(s, d);
            if (lane >= d) s += t;
        }
        if (lane == 63 && wv < 4) sm.p1.wtmp[wv] = s;
        __syncthreads();
        if (wv == 0) {
            int t = (lane < 4) ? sm.p1.wtmp[lane] : 0;
#pragma unroll
            for (int d = 1; d < 4; d <<= 1) {
                int u = __shfl_up(t, d);
                if (lane >= d) t += u;
            }
            if (lane < 4) sm.p1.wtmp[lane] = t;
        }
        __syncthreads();
        if (tid < BNODES) {
            int pre = s + (wv ? sm.p1.wtmp[wv - 1] : 0) - v;
            sm.p1.ofs[tid] = pre;
            sm.p1.cur[tid] = pre;
            int node = nbase + tid;
            if (node < n) {                               // dinv-scaled feats
                float di = rsqrtf((float)v + 1.0f);
                float* xo = xs + ((size_t)node << 3);     // padded row: 8 f
                xo[0] = xr0 * di; xo[1] = xr1 * di; xo[2] = xr2 * di;
                xo[3] = xr3 * di; xo[4] = xr4 * di;
            }
        }
    }
    // ---- barrier 2 (xs); overlap: counting-sort scatter (LDS-local) ----
    gbar_arrive(gbar, blk, tid);
    if (blk < nb) {
#pragma unroll
        for (int j = 0; j < RPT4; ++j) if (j < nv4) {
            int p;
            p = atomicAdd(&sm.p1.cur[((unsigned)rc[j].x) >> 24], 1);
            sm.p1.stage2[p] = rc[j].x & 0x00FFFFFF;
            p = atomicAdd(&sm.p1.cur[((unsigned)rc[j].y) >> 24], 1);
            sm.p1.stage2[p] = rc[j].y & 0x00FFFFFF;
            p = atomicAdd(&sm.p1.cur[((unsigned)rc[j].z) >> 24], 1);
            sm.p1.stage2[p] = rc[j].z & 0x00FFFFFF;
            p = atomicAdd(&sm.p1.cur[((unsigned)rc[j].w) >> 24], 1);
            sm.p1.stage2[p] = rc[j].w & 0x00FFFFFF;
        }
        if (rtv) {
            int p = atomicAdd(&sm.p1.cur[((unsigned)rt) >> 24], 1);
            sm.p1.stage2[p] = rt & 0x00FFFFFF;
        }
    }
    gbar_wait(gbar, 2 * G, tid);

    // ---------- phase B: layer-1 aggregation from LDS-resident stage2 ------
    if (blk < nb) {
        int t2 = tid >> 1, half = tid & 1;                // 2 threads/node
        int node = nbase + t2;
        if (node < n) {
            int beg = sm.p1.ofs[t2], dg = sm.p1.cnt[t2];
            float a0 = 0.f, a1 = 0.f, a2 = 0.f, a3 = 0.f, a4 = 0.f;
            if (!half) {                                  // self-loop term
                const float* xo = xs + ((size_t)node << 3);
                a0 = xo[0]; a1 = xo[1]; a2 = xo[2]; a3 = xo[3]; a4 = xo[4];
            }
            for (int e = beg + half; e < beg + dg; e += 2) {
                int sidx = sm.p1.stage2[e];
                const float* xr = xs + ((size_t)sidx << 3);
                float4 q = *(const float4*)xr;
                float q4 = xr[4];
                a0 += q.x; a1 += q.y; a2 += q.z; a3 += q.w; a4 += q4;
            }
            a0 += __shfl_xor(a0, 1); a1 += __shfl_xor(a1, 1);
            a2 += __shfl_xor(a2, 1); a3 += __shfl_xor(a3, 1);
            a4 += __shfl_xor(a4, 1);
            if (!half) {
                float di = rsqrtf((float)dg + 1.0f);
                a0 *= di; a1 *= di; a2 *= di; a3 *= di; a4 *= di;
                float sum = 0.f;
#pragma unroll
                for (int c = 0; c < 32; ++c) {
                    float z = sm.p1.bb1[c] + a0 * sm.p1.w1[c]
                            + a1 * sm.p1.w1[32 + c] + a2 * sm.p1.w1[64 + c]
                            + a3 * sm.p1.w1[96 + c] + a4 * sm.p1.w1[128 + c];
                    sum += fmaxf(z, 0.f) * sm.p1.w2[c];
                }
                h2s[node] = sum * di;                     // pre-scale src dinv
            }
        }
    }
    // ---- barrier 3 (h2s) ----
    gbar_arrive(gbar, blk, tid);
    gbar_wait(gbar, 3 * G, tid);

    // ---------- phase C: layer-2 from LDS-resident stage2 ------------------
    if (blk < nb) {
        int t2 = tid >> 1, half = tid & 1;
        int node = nbase + t2;
        if (node >= n) return;
        int beg = sm.p1.ofs[t2], dg = sm.p1.cnt[t2];
        float a = 0.f;
        for (int e = beg + half; e < beg + dg; e += 2)
            a += h2s[sm.p1.stage2[e]];
        a += __shfl_xor(a, 1);
        if (!half) {
            float di = rsqrtf((float)dg + 1.0f);
            float vv = di * (a + h2s[node]) + b2[0];
            out[node] = 1.0f / (1.0f + __expf(-vv));
        }
    }
}

// ===================== fallback: verified R16 pipeline =====================

__global__ __launch_bounds__(512) void k_part(const int* __restrict__ src,
                                              const int* __restrict__ dst, int E,
                                              int* __restrict__ bcur,
                                              int* __restrict__ pairs) {
    __shared__ int sp[CHUNK];
    __shared__ unsigned short sb[CHUNK];
    __shared__ int cnt[NBK], ofs[NBK], cur[NBK], gbase[NBK];
    int tid = threadIdx.x;
    int base = blockIdx.x * CHUNK;
    int m = min(CHUNK, E - base);

    if (tid < NBK) cnt[tid] = 0;
    __syncthreads();
    for (int i = tid; i < m; i += 2 * 512) {
        int i1 = i + 512;
        int k0 = dst[base + i] >> NB_SHIFT;
        int k1 = (i1 < m) ? (dst[base + i1] >> NB_SHIFT) : -1;
        atomicAdd(&cnt[k0], 1);
        if (k1 >= 0) atomicAdd(&cnt[k1], 1);
    }
    __syncthreads();
    int v = cnt[tid];
    ofs[tid] = v;
    __syncthreads();
    for (int off = 1; off < NBK; off <<= 1) {
        int u = (tid >= off) ? ofs[tid - off] : 0;
        __syncthreads();
        ofs[tid] += u;
        __syncthreads();
    }
    int pre = ofs[tid] - v;
    ofs[tid] = pre;
    cur[tid] = pre;
    gbase[tid] = (tid << CAP_SHIFT) + (v ? atomicAdd(&bcur[tid], v) : 0);
    __syncthreads();
    for (int i = tid; i < m; i += 4 * 512) {
        int ia = i + 512, ib = i + 1024, ic = i + 1536;
        int s0 = src[base + i], d0 = dst[base + i];
        int s1 = 0, d1 = 0, s2 = 0, d2 = 0, s3 = 0, d3 = 0;
        if (ia < m) { s1 = src[base + ia]; d1 = dst[base + ia]; }
        if (ib < m) { s2 = src[base + ib]; d2 = dst[base + ib]; }
        if (ic < m) { s3 = src[base + ic]; d3 = dst[base + ic]; }
        int b0 = d0 >> NB_SHIFT;
        int p0 = atomicAdd(&cur[b0], 1);
        sp[p0] = ((d0 & (BNODES - 1)) << 24) | s0;
        sb[p0] = (unsigned short)b0;
        if (ia < m) {
            int b1 = d1 >> NB_SHIFT;
            int p1 = atomicAdd(&cur[b1], 1);
            sp[p1] = ((d1 & (BNODES - 1)) << 24) | s1;
            sb[p1] = (unsigned short)b1;
        }
        if (ib < m) {
            int b2 = d2 >> NB_SHIFT;
            int p2 = atomicAdd(&cur[b2], 1);
            sp[p2] = ((d2 & (BNODES - 1)) << 24) | s2;
            sb[p2] = (unsigned short)b2;
        }
        if (ic < m) {
            int b3 = d3 >> NB_SHIFT;
            int p3 = atomicAdd(&cur[b3], 1);
            sp[p3] = ((d3 & (BNODES - 1)) << 24) | s3;
            sb[p3] = (unsigned short)b3;
        }
    }
    __syncthreads();
    for (int i = tid; i < m; i += 512) {
        int b = sb[i];
        pairs[gbase[b] + (i - ofs[b])] = sp[i];
    }
}

__global__ __launch_bounds__(512) void k_sorta(const int* __restrict__ pairs,
                                               const int* __restrict__ bcur,
                                               const float* __restrict__ x,
                                               float* __restrict__ dinv,
                                               float* __restrict__ xs,
                                               int* __restrict__ nofs,
                                               int* __restrict__ deg, int n) {
    __shared__ int cnt[BNODES], scn[BNODES];
    int tid = threadIdx.x;
    int b = blockIdx.x;
    int base = b << CAP_SHIFT;
    int len = min(bcur[b], CAP);

    if (tid < BNODES) cnt[tid] = 0;
    __syncthreads();
    for (int i = tid; i < len; i += 512)
        atomicAdd(&cnt[((unsigned)pairs[base + i]) >> 24], 1);
    __syncthreads();
    int v = (tid < BNODES) ? cnt[tid] : 0;
    if (tid < BNODES) scn[tid] = v;
    __syncthreads();
    for (int off = 1; off < BNODES; off <<= 1) {
        int u = (tid < BNODES && tid >= off) ? scn[tid - off] : 0;
        __syncthreads();
        if (tid < BNODES) scn[tid] += u;
        __syncthreads();
    }
    if (tid < BNODES) {
        int node = (b << NB_SHIFT) + tid;
        if (node < n) {
            nofs[node] = base + scn[tid] - v;
            deg[node] = v;
            float di = rsqrtf((float)v + 1.0f);
            dinv[node] = di;
            const float* xr = x + (size_t)node * 5;
            float* xo = xs + ((size_t)node << 3);
#pragma unroll
            for (int k = 0; k < 5; ++k) xo[k] = xr[k] * di;
        }
    }
}

__global__ __launch_bounds__(512) void k_sortagg1(int* __restrict__ pairs,
                                                  const int* __restrict__ bcur,
                                                  const int* __restrict__ nofs,
                                                  const int* __restrict__ deg,
                                                  const float* __restrict__ xs,
                                                  const float* __restrict__ dinv,
                                                  const float* __restrict__ W1,
                                                  const float* __restrict__ b1,
                                                  const float* __restrict__ W2,
                                                  float* __restrict__ h2s, int n) {
    __shared__ int stage2[CAP];
    __shared__ int ofs[BNODES], cnt[BNODES], cur[BNODES];
    __shared__ float w1[160], bb1[32], w2[32];
    int tid = threadIdx.x;
    int b = blockIdx.x;
    int nbase = b << NB_SHIFT;
    int base = b << CAP_SHIFT;
    int len = min(bcur[b], CAP);

    if (tid < 160) w1[tid] = W1[tid];
    else if (tid < 192) bb1[tid - 160] = b1[tid - 160];
    else if (tid < 224) w2[tid - 192] = W2[tid - 192];
    if (tid < BNODES) {
        int node = nbase + tid;
        int o = 0, c = 0;
        if (node < n) { o = nofs[node] - base; c = deg[node]; }
        ofs[tid] = o; cnt[tid] = c; cur[tid] = o;
    }
    __syncthreads();
    for (int i = tid; i < len; i += 2048) {
        int ia = i + 512, ib = i + 1024, ic = i + 1536;
        int v0 = pairs[base + i];
        int v1 = (ia < len) ? pairs[base + ia] : -1;
        int v2 = (ib < len) ? pairs[base + ib] : -1;
        int v3 = (ic < len) ? pairs[base + ic] : -1;
        int p0 = atomicAdd(&cur[((unsigned)v0) >> 24], 1);
        stage2[p0] = v0 & 0x00FFFFFF;
        if (v1 != -1) {
            int p1 = atomicAdd(&cur[((unsigned)v1) >> 24], 1);
            stage2[p1] = v1 & 0x00FFFFFF;
        }
        if (v2 != -1) {
            int p2 = atomicAdd(&cur[((unsigned)v2) >> 24], 1);
            stage2[p2] = v2 & 0x00FFFFFF;
        }
        if (v3 != -1) {
            int p3 = atomicAdd(&cur[((unsigned)v3) >> 24], 1);
            stage2[p3] = v3 & 0x00FFFFFF;
        }
    }
    __syncthreads();
    {
        int len4 = len >> 2;
        const int4* s4 = (const int4*)stage2;
        int4* p4 = (int4*)(pairs + base);
        for (int i = tid; i < len4; i += 512) p4[i] = s4[i];
        for (int i = (len4 << 2) + tid; i < len; i += 512)
            pairs[base + i] = stage2[i];
    }
    int t2 = tid >> 1, half = tid & 1;
    int node = nbase + t2;
    if (node >= n) return;
    int beg = ofs[t2], dg = cnt[t2];
    float a0 = 0.f, a1 = 0.f, a2 = 0.f, a3 = 0.f, a4 = 0.f;
    if (!half) {
        const float* xo = xs + ((size_t)node << 3);
        a0 = xo[0]; a1 = xo[1]; a2 = xo[2]; a3 = xo[3]; a4 = xo[4];
    }
    for (int e = beg + half; e < beg + dg; e += 2) {
        int s = stage2[e];
        const float* xr = xs + ((size_t)s << 3);
        float4 q = *(const float4*)xr;
        float q4 = xr[4];
        a0 += q.x; a1 += q.y; a2 += q.z; a3 += q.w; a4 += q4;
    }
    a0 += __shfl_xor(a0, 1); a1 += __shfl_xor(a1, 1); a2 += __shfl_xor(a2, 1);
    a3 += __shfl_xor(a3, 1); a4 += __shfl_xor(a4, 1);
    if (half) return;
    float di = dinv[node];
    a0 *= di; a1 *= di; a2 *= di; a3 *= di; a4 *= di;
    float sum = 0.f;
#pragma unroll
    for (int c = 0; c < 32; ++c) {
        float z = bb1[c] + a0 * w1[c] + a1 * w1[32 + c] + a2 * w1[64 + c]
                         + a3 * w1[96 + c] + a4 * w1[128 + c];
        sum += fmaxf(z, 0.f) * w2[c];
    }
    h2s[node] = sum * di;
}

__global__ __launch_bounds__(256) void k_agg2(const int* __restrict__ pairs,
                                              const int* __restrict__ nofs,
                                              const int* __restrict__ deg,
                                              const float* __restrict__ h2s,
                                              const float* __restrict__ dinv,
                                              const float* __restrict__ b2,
                                              float* __restrict__ out, int n) {
    int tid = threadIdx.x;
    int node = blockIdx.x * 64 + (tid >> 2);
    int q = tid & 3;
    if (node >= n) return;
    int beg = nofs[node], dg = deg[node];
    float a = 0.f;
    for (int e = beg + q; e < beg + dg; e += 4) a += h2s[pairs[e]];
    a += __shfl_xor(a, 1);
    a += __shfl_xor(a, 2);
    if (q) return;
    float v = dinv[node] * (a + h2s[node]) + b2[0];
    out[node] = 1.0f / (1.0f + __expf(-v));
}

extern "C" void kernel_launch(void* const* d_in, const int* in_sizes, int n_in,
                              void* d_out, int out_size, void* d_ws, size_t ws_size,
                              hipStream_t stream) {
    const float* x  = (const float*)d_in[0];
    const int*   ei = (const int*)d_in[1];
    const float* W1 = (const float*)d_in[2];
    const float* b1 = (const float*)d_in[3];
    const float* W2 = (const float*)d_in[4];
    const float* b2 = (const float*)d_in[5];
    float* out = (float*)d_out;

    const int n = in_sizes[0] / 5;       // 100000
    const int E = in_sizes[1] / 2;       // 2500000
    const int* src = ei;
    const int* dst = ei + E;
    const int nb = (n + BNODES - 1) >> NB_SHIFT;   // 391

    // unified ws (4B units): [pairs (nb+1)<<13][bcur NBK][gbar 8*GBS]
    //                        [deg n][nofs n][dinv n][h2s n][xs 8n]
    int* wsi = (int*)d_ws;
    int*   pairs = wsi;
    int*   bcur  = wsi + ((size_t)(nb + 1) << CAP_SHIFT);
    int*   gbar  = bcur + NBK;
    int*   deg   = gbar + 8 * GBS;
    int*   nofs  = deg + n;
    float* dinv  = (float*)(nofs + n);
    float* h2s   = dinv + n;
    float* xs    = h2s + n;

    const int nchunk = (E + CHUNK - 1) / CHUNK;    // 512
    const int g = nchunk > nb ? nchunk : nb;       // 512

    // one-time host-side gate: can g blocks be co-resident?
    static int use_coop = -1;
    if (use_coop < 0) {
        int dev = 0, ncu = 0, maxb = 0;
        hipGetDevice(&dev);
        hipDeviceGetAttribute(&ncu, hipDeviceAttributeMultiprocessorCount, dev);
        hipError_t e = hipOccupancyMaxActiveBlocksPerMultiprocessor(
                &maxb, k_fused, PBLK, 0);
        int coop = 0;
        hipDeviceGetAttribute(&coop, hipDeviceAttributeCooperativeLaunch, dev);
        use_coop = (e == hipSuccess && coop && (long)maxb * ncu >= g) ? 1 : 0;
    }

    hipMemsetAsync(bcur, 0, (NBK + 8 * GBS) * sizeof(int), stream);

    if (use_coop) {
        void* args[] = {(void*)&src, (void*)&dst, (void*)&E, (void*)&x,
                        (void*)&W1, (void*)&b1, (void*)&W2, (void*)&b2,
                        (void*)&out, (void*)&pairs, (void*)&bcur, (void*)&gbar,
                        (void*)&h2s, (void*)&xs, (void*)&n, (void*)&nb};
        hipError_t e = hipLaunchCooperativeKernel((const void*)k_fused,
                                                  dim3(g), dim3(PBLK),
                                                  args, 0, stream);
        if (e == hipSuccess) return;
        use_coop = 0;                    // launch refused -> permanent fallback
    }

    // fallback: verified R16 pipeline
    const int nagg = (n + 63) / 64;
    k_part<<<nchunk, 512, 0, stream>>>(src, dst, E, bcur, pairs);
    k_sorta<<<nb, 512, 0, stream>>>(pairs, bcur, x, dinv, xs, nofs, deg, n);
    k_sortagg1<<<nb, 512, 0, stream>>>(pairs, bcur, nofs, deg, xs, dinv,
                                       W1, b1, W2, h2s, n);
    k_agg2<<<nagg, 256, 0, stream>>>(pairs, nofs, deg, h2s, dinv, b2, out, n);
}